// Round 1
// baseline (745.351 us; speedup 1.0000x reference)
//
#include <hip/hip_runtime.h>
#include <hip/hip_bf16.h>

// ---------------------------------------------------------------------------
// PairRepulsionSwitch: per-edge ZBL + r^-12 repulsion, quarter-summed to both
// endpoint nodes.
//
// Strategy:
//   1. prep kernel: per-node Z = one_hot . atomic_numbers, and Z^0.23
//      (hoists the expensive powf out of the 6.4M-edge loop; 800KB table is
//      L2-resident).
//   2. edge kernel: 4 edges/thread (float4/int4 coalesced loads for lengths
//      and indices), gather float2 {Z, Z^0.23} per endpoint, ~4 __expf per
//      edge, two HW fp32 atomics (unsafeAtomicAdd -> global_atomic_add_f32).
// ---------------------------------------------------------------------------

#define KE_CONST 14.3996454784255f
// a = 0.88534 * A0 / (Zi^0.23 + Zj^0.23);  x = r/a = r * (sum) * INV_AC
constexpr float INV_AC = 1.0f / (0.88534f * 0.52917721092f);

__global__ void zero_out_kernel(float* __restrict__ out, int n) {
    int i = blockIdx.x * blockDim.x + threadIdx.x;
    if (i < n) out[i] = 0.0f;
}

__global__ void prep_nodes_kernel(const float* __restrict__ node_attrs,
                                  const float* __restrict__ atomic_numbers,
                                  float2* __restrict__ ztab,
                                  int n_nodes, int n_elem) {
    int i = blockIdx.x * blockDim.x + threadIdx.x;
    if (i >= n_nodes) return;
    float z = 0.0f;
    for (int k = 0; k < n_elem; ++k)
        z += node_attrs[i * n_elem + k] * atomic_numbers[k];
    ztab[i] = make_float2(z, powf(z, 0.23f));
}

__device__ __forceinline__ float edge_energy(float len, float2 zi, float2 zj,
                                             float inv_rmax) {
    float r = fmaxf(len, 0.2f);                 // R_MIN clamp
    float inv_r = 1.0f / r;

    // poly cutoff: (1 - clip(r/r_max,0,1))^6
    float u = fmaxf(1.0f - r * inv_rmax, 0.0f);
    float u2 = u * u;
    float pc = u2 * u2 * u2;

    // ZBL screened Coulomb
    float x = r * (zi.y + zj.y) * INV_AC;
    float phi = 0.1818f   * __expf(-3.2f    * x)
              + 0.5099f   * __expf(-0.9423f * x)
              + 0.2802f   * __expf(-0.4029f * x)
              + 0.02817f  * __expf(-0.2016f * x);
    float v_zbl = KE_CONST * zi.x * zj.x * phi * inv_r * pc;

    // C12 / r^12 with smoothstep switch at rc=1.5, width=0.2
    float ir2 = inv_r * inv_r;
    float ir4 = ir2 * ir2;
    float ir12 = ir4 * ir4 * ir4;
    float t = fminf(fmaxf((1.5f - r) * 5.0f, 0.0f), 1.0f);  // /width=0.2
    float sm = t * t * (3.0f - 2.0f * t);
    float v_r12 = 1e-4f * ir12 * pc * sm;

    return 0.25f * (v_zbl + v_r12);             // quarter to each endpoint
}

__global__ __launch_bounds__(256) void edge_kernel(
    const float* __restrict__ lengths,
    const int* __restrict__ src_idx,
    const int* __restrict__ dst_idx,
    const float2* __restrict__ ztab,
    const float* __restrict__ rmax_ptr,
    float* __restrict__ out,
    int n_edges) {
    const float inv_rmax = 1.0f / rmax_ptr[0];
    int t = blockIdx.x * blockDim.x + threadIdx.x;
    int base = t * 4;
    if (base + 3 < n_edges) {
        float4 L = *reinterpret_cast<const float4*>(lengths + base);
        int4 S = *reinterpret_cast<const int4*>(src_idx + base);
        int4 D = *reinterpret_cast<const int4*>(dst_idx + base);
        float l[4] = {L.x, L.y, L.z, L.w};
        int   s[4] = {S.x, S.y, S.z, S.w};
        int   d[4] = {D.x, D.y, D.z, D.w};
        float2 zs[4], zd[4];
#pragma unroll
        for (int k = 0; k < 4; ++k) { zs[k] = ztab[s[k]]; zd[k] = ztab[d[k]]; }
#pragma unroll
        for (int k = 0; k < 4; ++k) {
            float q = edge_energy(l[k], zs[k], zd[k], inv_rmax);
            unsafeAtomicAdd(&out[s[k]], q);
            unsafeAtomicAdd(&out[d[k]], q);
        }
    } else if (base < n_edges) {
        for (int e = base; e < n_edges; ++e) {
            int si = src_idx[e], di = dst_idx[e];
            float q = edge_energy(lengths[e], ztab[si], ztab[di], inv_rmax);
            unsafeAtomicAdd(&out[si], q);
            unsafeAtomicAdd(&out[di], q);
        }
    }
}

extern "C" void kernel_launch(void* const* d_in, const int* in_sizes, int n_in,
                              void* d_out, int out_size, void* d_ws, size_t ws_size,
                              hipStream_t stream) {
    const float* lengths        = (const float*)d_in[0];
    const float* node_attrs     = (const float*)d_in[1];
    const int*   edge_index     = (const int*)d_in[2];
    const float* atomic_numbers = (const float*)d_in[3];
    const float* rmax_ptr       = (const float*)d_in[4];

    int n_edges = in_sizes[0];
    int n_elem  = in_sizes[3];
    int n_nodes = out_size;

    float*  out  = (float*)d_out;
    float2* ztab = (float2*)d_ws;   // n_nodes * 8 bytes

    int nb_nodes = (n_nodes + 255) / 256;
    zero_out_kernel<<<nb_nodes, 256, 0, stream>>>(out, n_nodes);
    prep_nodes_kernel<<<nb_nodes, 256, 0, stream>>>(node_attrs, atomic_numbers,
                                                    ztab, n_nodes, n_elem);

    int n_thread4 = (n_edges + 3) / 4;
    int nb_edges = (n_thread4 + 255) / 256;
    edge_kernel<<<nb_edges, 256, 0, stream>>>(
        lengths, edge_index, edge_index + n_edges, ztab, rmax_ptr, out, n_edges);
}

// Round 2
// 722.657 us; speedup vs baseline: 1.0314x; 1.0314x over previous
//
#include <hip/hip_runtime.h>
#include <hip/hip_bf16.h>

// ---------------------------------------------------------------------------
// PairRepulsionSwitch: per-edge ZBL + r^-12 repulsion, quarter-summed to both
// endpoint nodes.
//
// R1 finding: 12.8M fp32 atomics into 100K nodes = 128 RMWs/address; same-line
// RMW chains serialize at the TCC (observed 655us ~= 12.8M * 16cyc / 128ch).
// R2 strategy: R-way replicated accumulators in workspace (replica chosen by
// thread id) to cut same-address dependency chains by R, then one reduce
// kernel sums replicas into d_out.
//
// Workspace layout: [R * stride floats: replicas][n_nodes float2: ztab]
// ---------------------------------------------------------------------------

#define KE_CONST 14.3996454784255f
constexpr float INV_AC = 1.0f / (0.88534f * 0.52917721092f);

__global__ void prep_nodes_kernel(const float* __restrict__ node_attrs,
                                  const float* __restrict__ atomic_numbers,
                                  float2* __restrict__ ztab,
                                  int n_nodes, int n_elem) {
    int i = blockIdx.x * blockDim.x + threadIdx.x;
    if (i >= n_nodes) return;
    float z = 0.0f;
    for (int k = 0; k < n_elem; ++k)
        z += node_attrs[i * n_elem + k] * atomic_numbers[k];
    ztab[i] = make_float2(z, powf(z, 0.23f));
}

__device__ __forceinline__ float edge_energy(float len, float2 zi, float2 zj,
                                             float inv_rmax) {
    float r = fmaxf(len, 0.2f);                 // R_MIN clamp
    float inv_r = 1.0f / r;

    // poly cutoff: (1 - clip(r/r_max,0,1))^6
    float u = fmaxf(1.0f - r * inv_rmax, 0.0f);
    float u2 = u * u;
    float pc = u2 * u2 * u2;

    // ZBL screened Coulomb
    float x = r * (zi.y + zj.y) * INV_AC;
    float phi = 0.1818f   * __expf(-3.2f    * x)
              + 0.5099f   * __expf(-0.9423f * x)
              + 0.2802f   * __expf(-0.4029f * x)
              + 0.02817f  * __expf(-0.2016f * x);
    float v_zbl = KE_CONST * zi.x * zj.x * phi * inv_r * pc;

    // C12 / r^12 with smoothstep switch at rc=1.5, width=0.2
    float ir2 = inv_r * inv_r;
    float ir4 = ir2 * ir2;
    float ir12 = ir4 * ir4 * ir4;
    float t = fminf(fmaxf((1.5f - r) * 5.0f, 0.0f), 1.0f);  // /width=0.2
    float sm = t * t * (3.0f - 2.0f * t);
    float v_r12 = 1e-4f * ir12 * pc * sm;

    return 0.25f * (v_zbl + v_r12);             // quarter to each endpoint
}

__global__ __launch_bounds__(256) void edge_kernel(
    const float* __restrict__ lengths,
    const int* __restrict__ src_idx,
    const int* __restrict__ dst_idx,
    const float2* __restrict__ ztab,
    const float* __restrict__ rmax_ptr,
    float* __restrict__ repl,       // R replicas, each `stride` floats
    int stride, unsigned rmask,     // rmask = R-1 (R power of two)
    int n_edges) {
    const float inv_rmax = 1.0f / rmax_ptr[0];
    int t = blockIdx.x * blockDim.x + threadIdx.x;
    float* __restrict__ myout = repl + (size_t)((unsigned)t & rmask) * stride;
    int base = t * 4;
    if (base + 3 < n_edges) {
        float4 L = *reinterpret_cast<const float4*>(lengths + base);
        int4 S = *reinterpret_cast<const int4*>(src_idx + base);
        int4 D = *reinterpret_cast<const int4*>(dst_idx + base);
        float l[4] = {L.x, L.y, L.z, L.w};
        int   s[4] = {S.x, S.y, S.z, S.w};
        int   d[4] = {D.x, D.y, D.z, D.w};
        float2 zs[4], zd[4];
#pragma unroll
        for (int k = 0; k < 4; ++k) { zs[k] = ztab[s[k]]; zd[k] = ztab[d[k]]; }
#pragma unroll
        for (int k = 0; k < 4; ++k) {
            float q = edge_energy(l[k], zs[k], zd[k], inv_rmax);
            unsafeAtomicAdd(&myout[s[k]], q);
            unsafeAtomicAdd(&myout[d[k]], q);
        }
    } else if (base < n_edges) {
        for (int e = base; e < n_edges; ++e) {
            int si = src_idx[e], di = dst_idx[e];
            float q = edge_energy(lengths[e], ztab[si], ztab[di], inv_rmax);
            unsafeAtomicAdd(&myout[si], q);
            unsafeAtomicAdd(&myout[di], q);
        }
    }
}

__global__ void reduce_kernel(const float* __restrict__ repl,
                              int stride, int R,
                              float* __restrict__ out, int n_nodes) {
    int i = blockIdx.x * blockDim.x + threadIdx.x;
    if (i >= n_nodes) return;
    float s = 0.0f;
    for (int r = 0; r < R; ++r)
        s += repl[(size_t)r * stride + i];
    out[i] = s;
}

extern "C" void kernel_launch(void* const* d_in, const int* in_sizes, int n_in,
                              void* d_out, int out_size, void* d_ws, size_t ws_size,
                              hipStream_t stream) {
    const float* lengths        = (const float*)d_in[0];
    const float* node_attrs     = (const float*)d_in[1];
    const int*   edge_index     = (const int*)d_in[2];
    const float* atomic_numbers = (const float*)d_in[3];
    const float* rmax_ptr       = (const float*)d_in[4];

    int n_edges = in_sizes[0];
    int n_elem  = in_sizes[3];
    int n_nodes = out_size;

    float* out = (float*)d_out;

    // Replica stride: pad to keep 8B alignment and break power-of-2 aliasing.
    int stride = ((n_nodes + 49) / 2) * 2;   // n_nodes + ~48, even
    // Pick largest power-of-two R <= 16 that fits alongside ztab.
    int R = 16;
    while (R > 1 &&
           (size_t)R * stride * sizeof(float) + (size_t)n_nodes * sizeof(float2)
               > ws_size)
        R >>= 1;

    float*  repl = (float*)d_ws;
    float2* ztab = (float2*)((char*)d_ws + (size_t)R * stride * sizeof(float));

    hipMemsetAsync(repl, 0, (size_t)R * stride * sizeof(float), stream);

    int nb_nodes = (n_nodes + 255) / 256;
    prep_nodes_kernel<<<nb_nodes, 256, 0, stream>>>(node_attrs, atomic_numbers,
                                                    ztab, n_nodes, n_elem);

    int n_thread4 = (n_edges + 3) / 4;
    int nb_edges = (n_thread4 + 255) / 256;
    edge_kernel<<<nb_edges, 256, 0, stream>>>(
        lengths, edge_index, edge_index + n_edges, ztab, rmax_ptr,
        repl, stride, (unsigned)(R - 1), n_edges);

    reduce_kernel<<<nb_nodes, 256, 0, stream>>>(repl, stride, R, out, n_nodes);
}

// Round 3
// 373.108 us; speedup vs baseline: 1.9977x; 1.9369x over previous
//
#include <hip/hip_runtime.h>
#include <hip/hip_bf16.h>
#include <stdint.h>

// ---------------------------------------------------------------------------
// PairRepulsionSwitch: per-edge ZBL + r^-12 repulsion, quarter-summed to both
// endpoint nodes.
//
// R1: 12.8M device-scope fp32 atomics -> 655us, WRITE_SIZE = 32B/atomic.
// R2: 16-way replicated accumulators -> 621us, WRITE_SIZE unchanged.
//     => atomics are executed memory-side at a hard ~20G atomics/s rate;
//        distribution doesn't matter, the atomic COUNT must go away.
// R3: deterministic bucket binning, zero global atomics:
//     hist -> column scan -> total scan -> scatter(4B packed records at exact
//     offsets via LDS cursors) -> per-bucket LDS reduce.
//     Records: top 8 bits = node&255 (local id), low 24 = top-24 bits of fp32
//     q (rel err 1.5e-5 << threshold).
// Falls back to the R2 atomic path if ws_size is too small.
// ---------------------------------------------------------------------------

#define KE_CONST 14.3996454784255f
constexpr float INV_AC = 1.0f / (0.88534f * 0.52917721092f);

#define CHUNK 16384          // edges per block in hist/scatter
#define MAXB 1024            // max buckets (supports n_nodes <= 256K)

// ---------------------------------------------------------------- shared math
__device__ __forceinline__ float edge_energy(float len, float2 zi, float2 zj,
                                             float inv_rmax) {
    float r = fmaxf(len, 0.2f);                 // R_MIN clamp
    float inv_r = 1.0f / r;

    // poly cutoff: (1 - clip(r/r_max,0,1))^6
    float u = fmaxf(1.0f - r * inv_rmax, 0.0f);
    float u2 = u * u;
    float pc = u2 * u2 * u2;

    // ZBL screened Coulomb
    float x = r * (zi.y + zj.y) * INV_AC;
    float phi = 0.1818f   * __expf(-3.2f    * x)
              + 0.5099f   * __expf(-0.9423f * x)
              + 0.2802f   * __expf(-0.4029f * x)
              + 0.02817f  * __expf(-0.2016f * x);
    float v_zbl = KE_CONST * zi.x * zj.x * phi * inv_r * pc;

    // C12 / r^12 with smoothstep switch at rc=1.5, width=0.2
    float ir2 = inv_r * inv_r;
    float ir4 = ir2 * ir2;
    float ir12 = ir4 * ir4 * ir4;
    float t = fminf(fmaxf((1.5f - r) * 5.0f, 0.0f), 1.0f);  // /width=0.2
    float sm = t * t * (3.0f - 2.0f * t);
    float v_r12 = 1e-4f * ir12 * pc * sm;

    return 0.25f * (v_zbl + v_r12);             // quarter to each endpoint
}

__global__ void prep_nodes_kernel(const float* __restrict__ node_attrs,
                                  const float* __restrict__ atomic_numbers,
                                  float2* __restrict__ ztab,
                                  int n_nodes, int n_elem) {
    int i = blockIdx.x * blockDim.x + threadIdx.x;
    if (i >= n_nodes) return;
    float z = 0.0f;
    for (int k = 0; k < n_elem; ++k)
        z += node_attrs[i * n_elem + k] * atomic_numbers[k];
    ztab[i] = make_float2(z, powf(z, 0.23f));
}

// ------------------------------------------------------------- main pipeline
__global__ __launch_bounds__(256) void hist_kernel(
    const int* __restrict__ src, const int* __restrict__ dst,
    uint32_t* __restrict__ hist, int n_edges, int B) {
    __shared__ uint32_t h[MAXB];
    int blk = blockIdx.x;
    for (int i = threadIdx.x; i < B; i += 256) h[i] = 0;
    __syncthreads();
    int start = blk * CHUNK;
    int n_this = min(CHUNK, n_edges - start);
    if (n_this == CHUNK) {
#pragma unroll 4
        for (int it = 0; it < CHUNK / 1024; ++it) {
            int e = start + it * 1024 + threadIdx.x * 4;
            int4 S = *reinterpret_cast<const int4*>(src + e);
            int4 D = *reinterpret_cast<const int4*>(dst + e);
            atomicAdd(&h[S.x >> 8], 1u); atomicAdd(&h[D.x >> 8], 1u);
            atomicAdd(&h[S.y >> 8], 1u); atomicAdd(&h[D.y >> 8], 1u);
            atomicAdd(&h[S.z >> 8], 1u); atomicAdd(&h[D.z >> 8], 1u);
            atomicAdd(&h[S.w >> 8], 1u); atomicAdd(&h[D.w >> 8], 1u);
        }
    } else {
        for (int i = threadIdx.x; i < n_this; i += 256) {
            atomicAdd(&h[src[start + i] >> 8], 1u);
            atomicAdd(&h[dst[start + i] >> 8], 1u);
        }
    }
    __syncthreads();
    for (int i = threadIdx.x; i < B; i += 256)
        hist[(size_t)blk * B + i] = h[i];
}

// Column-wise exclusive scan: hist[blk][b] -> exclusive prefix within column b;
// totals[b] = column sum. Grid = B blocks.
__global__ __launch_bounds__(512) void scan_col_kernel(
    uint32_t* __restrict__ hist, uint32_t* __restrict__ totals, int NB, int B) {
    int b = blockIdx.x;
    __shared__ uint32_t buf[512];
    __shared__ uint32_t carry;
    if (threadIdx.x == 0) carry = 0;
    __syncthreads();
    for (int base0 = 0; base0 < NB; base0 += 512) {
        int blk = base0 + threadIdx.x;
        uint32_t v = (blk < NB) ? hist[(size_t)blk * B + b] : 0u;
        buf[threadIdx.x] = v;
        __syncthreads();
        for (int off = 1; off < 512; off <<= 1) {
            uint32_t t = (threadIdx.x >= off) ? buf[threadIdx.x - off] : 0u;
            __syncthreads();
            buf[threadIdx.x] += t;
            __syncthreads();
        }
        uint32_t incl = buf[threadIdx.x];
        if (blk < NB) hist[(size_t)blk * B + b] = carry + (incl - v);
        __syncthreads();
        if (threadIdx.x == 511) carry += incl;   // chunk total
        __syncthreads();
    }
    if (threadIdx.x == 0) totals[b] = carry;
}

// Exclusive scan of totals[B] -> bases[B+1]. One block, 1024 threads.
__global__ __launch_bounds__(1024) void scan_total_kernel(
    const uint32_t* __restrict__ totals, uint32_t* __restrict__ bases, int B) {
    __shared__ uint32_t buf[1024];
    uint32_t v = (threadIdx.x < (unsigned)B) ? totals[threadIdx.x] : 0u;
    buf[threadIdx.x] = v;
    __syncthreads();
    for (int off = 1; off < 1024; off <<= 1) {
        uint32_t t = (threadIdx.x >= off) ? buf[threadIdx.x - off] : 0u;
        __syncthreads();
        buf[threadIdx.x] += t;
        __syncthreads();
    }
    uint32_t incl = buf[threadIdx.x];
    if (threadIdx.x < (unsigned)B) bases[threadIdx.x] = incl - v;
    if (threadIdx.x == (unsigned)(B - 1)) bases[B] = incl;
}

__device__ __forceinline__ uint32_t pack_rec(int node, float q) {
    uint32_t qb = __float_as_uint(q);
    return ((uint32_t)(node & 255) << 24) | (qb >> 8);
}

__global__ __launch_bounds__(256) void scatter_kernel(
    const float* __restrict__ lengths,
    const int* __restrict__ src, const int* __restrict__ dst,
    const float2* __restrict__ ztab,
    const float* __restrict__ rmax_ptr,
    const uint32_t* __restrict__ hist,      // exclusive offsets per (blk,b)
    const uint32_t* __restrict__ bases,     // bucket bases
    uint32_t* __restrict__ records,
    int n_edges, int B) {
    __shared__ int cur[MAXB];
    int blk = blockIdx.x;
    for (int i = threadIdx.x; i < B; i += 256)
        cur[i] = (int)(hist[(size_t)blk * B + i] + bases[i]);
    __syncthreads();
    const float inv_rmax = 1.0f / rmax_ptr[0];
    int start = blk * CHUNK;
    int n_this = min(CHUNK, n_edges - start);
    if (n_this == CHUNK) {
        for (int it = 0; it < CHUNK / 1024; ++it) {
            int e = start + it * 1024 + threadIdx.x * 4;
            float4 L = *reinterpret_cast<const float4*>(lengths + e);
            int4 S = *reinterpret_cast<const int4*>(src + e);
            int4 D = *reinterpret_cast<const int4*>(dst + e);
            float l[4] = {L.x, L.y, L.z, L.w};
            int s[4] = {S.x, S.y, S.z, S.w};
            int d[4] = {D.x, D.y, D.z, D.w};
            float2 zs[4], zd[4];
#pragma unroll
            for (int k = 0; k < 4; ++k) { zs[k] = ztab[s[k]]; zd[k] = ztab[d[k]]; }
#pragma unroll
            for (int k = 0; k < 4; ++k) {
                float q = edge_energy(l[k], zs[k], zd[k], inv_rmax);
                int ps = atomicAdd(&cur[s[k] >> 8], 1);
                records[ps] = pack_rec(s[k], q);
                int pd = atomicAdd(&cur[d[k] >> 8], 1);
                records[pd] = pack_rec(d[k], q);
            }
        }
    } else {
        for (int i = threadIdx.x; i < n_this; i += 256) {
            int e = start + i;
            int si = src[e], di = dst[e];
            float q = edge_energy(lengths[e], ztab[si], ztab[di], inv_rmax);
            int ps = atomicAdd(&cur[si >> 8], 1);
            records[ps] = pack_rec(si, q);
            int pd = atomicAdd(&cur[di >> 8], 1);
            records[pd] = pack_rec(di, q);
        }
    }
}

__global__ __launch_bounds__(256) void reduce_bucket_kernel(
    const uint32_t* __restrict__ records,
    const uint32_t* __restrict__ bases,
    float* __restrict__ out, int n_nodes) {
    int b = blockIdx.x;
    __shared__ float acc[256 * 4];
    for (int i = threadIdx.x; i < 1024; i += 256) acc[i] = 0.0f;
    __syncthreads();
    uint32_t s = bases[b], e = bases[b + 1];
    int rep = threadIdx.x & 3;
    for (uint32_t p = s + threadIdx.x; p < e; p += 256) {
        uint32_t rec = records[p];
        float q = __uint_as_float((rec & 0x00FFFFFFu) << 8);
        int local = (int)(rec >> 24);
        atomicAdd(&acc[local * 4 + rep], q);
    }
    __syncthreads();
    int node = (b << 8) + threadIdx.x;
    if (node < n_nodes)
        out[node] = acc[threadIdx.x * 4] + acc[threadIdx.x * 4 + 1]
                  + acc[threadIdx.x * 4 + 2] + acc[threadIdx.x * 4 + 3];
}

// ----------------------------------------------------------- fallback (R2)
__global__ void zero_out_kernel(float* __restrict__ out, int n) {
    int i = blockIdx.x * blockDim.x + threadIdx.x;
    if (i < n) out[i] = 0.0f;
}

__global__ __launch_bounds__(256) void edge_kernel_atomic(
    const float* __restrict__ lengths,
    const int* __restrict__ src_idx,
    const int* __restrict__ dst_idx,
    const float2* __restrict__ ztab,
    const float* __restrict__ rmax_ptr,
    float* __restrict__ out,
    int n_edges) {
    const float inv_rmax = 1.0f / rmax_ptr[0];
    int t = blockIdx.x * blockDim.x + threadIdx.x;
    int base = t * 4;
    if (base + 3 < n_edges) {
        float4 L = *reinterpret_cast<const float4*>(lengths + base);
        int4 S = *reinterpret_cast<const int4*>(src_idx + base);
        int4 D = *reinterpret_cast<const int4*>(dst_idx + base);
        float l[4] = {L.x, L.y, L.z, L.w};
        int s[4] = {S.x, S.y, S.z, S.w};
        int d[4] = {D.x, D.y, D.z, D.w};
        float2 zs[4], zd[4];
#pragma unroll
        for (int k = 0; k < 4; ++k) { zs[k] = ztab[s[k]]; zd[k] = ztab[d[k]]; }
#pragma unroll
        for (int k = 0; k < 4; ++k) {
            float q = edge_energy(l[k], zs[k], zd[k], inv_rmax);
            unsafeAtomicAdd(&out[s[k]], q);
            unsafeAtomicAdd(&out[d[k]], q);
        }
    } else if (base < n_edges) {
        for (int e = base; e < n_edges; ++e) {
            int si = src_idx[e], di = dst_idx[e];
            float q = edge_energy(lengths[e], ztab[si], ztab[di], inv_rmax);
            unsafeAtomicAdd(&out[si], q);
            unsafeAtomicAdd(&out[di], q);
        }
    }
}

// ---------------------------------------------------------------- launcher
extern "C" void kernel_launch(void* const* d_in, const int* in_sizes, int n_in,
                              void* d_out, int out_size, void* d_ws, size_t ws_size,
                              hipStream_t stream) {
    const float* lengths        = (const float*)d_in[0];
    const float* node_attrs     = (const float*)d_in[1];
    const int*   edge_index     = (const int*)d_in[2];
    const float* atomic_numbers = (const float*)d_in[3];
    const float* rmax_ptr       = (const float*)d_in[4];

    int n_edges = in_sizes[0];
    int n_elem  = in_sizes[3];
    int n_nodes = out_size;
    float* out = (float*)d_out;

    const int* src = edge_index;
    const int* dst = edge_index + n_edges;

    int B  = ((n_nodes - 1) >> 8) + 1;                  // 256 nodes/bucket
    int NB = (n_edges + CHUNK - 1) / CHUNK;

    // ws layout: records | hist(NB*B) | totals(B) | bases(B+1) | pad | ztab
    size_t rec_bytes   = (size_t)2 * n_edges * sizeof(uint32_t);
    size_t hist_bytes  = (size_t)NB * B * sizeof(uint32_t);
    size_t tot_bytes   = (size_t)B * sizeof(uint32_t);
    size_t base_bytes  = (size_t)(B + 1) * sizeof(uint32_t);
    size_t ztab_off    = rec_bytes + hist_bytes + tot_bytes + base_bytes;
    ztab_off = (ztab_off + 7) & ~(size_t)7;
    size_t need = ztab_off + (size_t)n_nodes * sizeof(float2);

    int nb_nodes = (n_nodes + 255) / 256;

    if (B <= MAXB && need <= ws_size) {
        uint32_t* records = (uint32_t*)d_ws;
        uint32_t* hist    = (uint32_t*)((char*)d_ws + rec_bytes);
        uint32_t* totals  = (uint32_t*)((char*)d_ws + rec_bytes + hist_bytes);
        uint32_t* bases   = (uint32_t*)((char*)d_ws + rec_bytes + hist_bytes + tot_bytes);
        float2*   ztab    = (float2*)((char*)d_ws + ztab_off);

        prep_nodes_kernel<<<nb_nodes, 256, 0, stream>>>(
            node_attrs, atomic_numbers, ztab, n_nodes, n_elem);
        hist_kernel<<<NB, 256, 0, stream>>>(src, dst, hist, n_edges, B);
        scan_col_kernel<<<B, 512, 0, stream>>>(hist, totals, NB, B);
        scan_total_kernel<<<1, 1024, 0, stream>>>(totals, bases, B);
        scatter_kernel<<<NB, 256, 0, stream>>>(
            lengths, src, dst, ztab, rmax_ptr, hist, bases, records, n_edges, B);
        reduce_bucket_kernel<<<B, 256, 0, stream>>>(records, bases, out, n_nodes);
    } else {
        // fallback: replicated-atomic path (R2)
        int stride = ((n_nodes + 49) / 2) * 2;
        int R = 16;
        while (R > 1 &&
               (size_t)R * stride * sizeof(float) + (size_t)n_nodes * sizeof(float2)
                   > ws_size)
            R >>= 1;
        float*  repl = (float*)d_ws;
        float2* ztab = (float2*)((char*)d_ws + (size_t)R * stride * sizeof(float));
        (void)repl;
        hipMemsetAsync(d_ws, 0, (size_t)R * stride * sizeof(float), stream);
        prep_nodes_kernel<<<nb_nodes, 256, 0, stream>>>(
            node_attrs, atomic_numbers, ztab, n_nodes, n_elem);
        zero_out_kernel<<<nb_nodes, 256, 0, stream>>>(out, n_nodes);
        int n_thread4 = (n_edges + 3) / 4;
        int nb_edges = (n_thread4 + 255) / 256;
        edge_kernel_atomic<<<nb_edges, 256, 0, stream>>>(
            lengths, src, dst, ztab, rmax_ptr, out, n_edges);
    }
}

// Round 4
// 327.534 us; speedup vs baseline: 2.2756x; 1.1391x over previous
//
#include <hip/hip_runtime.h>
#include <hip/hip_bf16.h>
#include <stdint.h>

// ---------------------------------------------------------------------------
// PairRepulsionSwitch: per-edge ZBL + r^-12 repulsion, quarter-summed to both
// endpoint nodes.
//
// R1/R2: global fp32 atomics are memory-side rate-limited (~20G/s) -> 655us.
// R3: binning pipeline -> 373us, but scatter wrote 4.4x (random-order 4B
//     stores -> partial-line writebacks) and grid of 391 blocks starved
//     occupancy (13%).
// R4: block-local counting sort in LDS: local hist -> local scan -> global
//     reservation via per-bucket atomic cursors (153K atomics total) ->
//     sorted placement in LDS -> coalesced segment emit. CHUNK=4096 (1563
//     blocks), buckets of 1024 nodes (B=98), reduce split 16-way/bucket.
//     Records: [10b local node | 22b truncated fp32 q].
// ---------------------------------------------------------------------------

#define KE_CONST 14.3996454784255f
constexpr float INV_AC = 1.0f / (0.88534f * 0.52917721092f);

#define CHUNK 4096           // edges per block (8192 records)
#define MAXB 512             // max buckets (n_nodes <= 512K)
#define BSH 10               // 1024 nodes per bucket
#define BMASK ((1 << BSH) - 1)
#define MAXS 16              // reduce split factor

// ---------------------------------------------------------------- shared math
__device__ __forceinline__ float edge_energy(float len, float2 zi, float2 zj,
                                             float inv_rmax) {
    float r = fmaxf(len, 0.2f);                 // R_MIN clamp
    float inv_r = 1.0f / r;

    // poly cutoff: (1 - clip(r/r_max,0,1))^6
    float u = fmaxf(1.0f - r * inv_rmax, 0.0f);
    float u2 = u * u;
    float pc = u2 * u2 * u2;

    // ZBL screened Coulomb
    float x = r * (zi.y + zj.y) * INV_AC;
    float phi = 0.1818f   * __expf(-3.2f    * x)
              + 0.5099f   * __expf(-0.9423f * x)
              + 0.2802f   * __expf(-0.4029f * x)
              + 0.02817f  * __expf(-0.2016f * x);
    float v_zbl = KE_CONST * zi.x * zj.x * phi * inv_r * pc;

    // C12 / r^12 with smoothstep switch at rc=1.5, width=0.2
    float ir2 = inv_r * inv_r;
    float ir4 = ir2 * ir2;
    float ir12 = ir4 * ir4 * ir4;
    float t = fminf(fmaxf((1.5f - r) * 5.0f, 0.0f), 1.0f);  // /width=0.2
    float sm = t * t * (3.0f - 2.0f * t);
    float v_r12 = 1e-4f * ir12 * pc * sm;

    return 0.25f * (v_zbl + v_r12);             // quarter to each endpoint
}

__global__ void prep_nodes_kernel(const float* __restrict__ node_attrs,
                                  const float* __restrict__ atomic_numbers,
                                  float2* __restrict__ ztab,
                                  int n_nodes, int n_elem) {
    int i = blockIdx.x * blockDim.x + threadIdx.x;
    if (i >= n_nodes) return;
    float z = 0.0f;
    for (int k = 0; k < n_elem; ++k)
        z += node_attrs[i * n_elem + k] * atomic_numbers[k];
    ztab[i] = make_float2(z, powf(z, 0.23f));
}

// ------------------------------------------------------- bucket totals (hist)
__global__ __launch_bounds__(256) void hist_tot_kernel(
    const int* __restrict__ src, const int* __restrict__ dst,
    uint32_t* __restrict__ totals, int n_edges, int B, int vec_ok) {
    __shared__ uint32_t h[MAXB];
    int tid = threadIdx.x;
    for (int i = tid; i < B; i += 256) h[i] = 0;
    __syncthreads();
    int start = blockIdx.x * CHUNK;
    int n_this = min(CHUNK, n_edges - start);
    if (n_this == CHUNK && vec_ok) {
        for (int it = 0; it < CHUNK / 1024; ++it) {
            int e = start + (it * 256 + tid) * 4;
            int4 S = *reinterpret_cast<const int4*>(src + e);
            int4 D = *reinterpret_cast<const int4*>(dst + e);
            atomicAdd(&h[S.x >> BSH], 1u); atomicAdd(&h[D.x >> BSH], 1u);
            atomicAdd(&h[S.y >> BSH], 1u); atomicAdd(&h[D.y >> BSH], 1u);
            atomicAdd(&h[S.z >> BSH], 1u); atomicAdd(&h[D.z >> BSH], 1u);
            atomicAdd(&h[S.w >> BSH], 1u); atomicAdd(&h[D.w >> BSH], 1u);
        }
    } else {
        for (int i = tid; i < n_this; i += 256) {
            atomicAdd(&h[src[start + i] >> BSH], 1u);
            atomicAdd(&h[dst[start + i] >> BSH], 1u);
        }
    }
    __syncthreads();
    for (int i = tid; i < B; i += 256)
        if (h[i]) atomicAdd(&totals[i], h[i]);
}

// Exclusive scan of totals -> bases[B+1]; also init gcur = bases. One block.
__global__ __launch_bounds__(MAXB) void scan_total_kernel(
    const uint32_t* __restrict__ totals, uint32_t* __restrict__ bases,
    uint32_t* __restrict__ gcur, int B) {
    __shared__ uint32_t buf[MAXB];
    int tid = threadIdx.x;
    uint32_t v = (tid < B) ? totals[tid] : 0u;
    buf[tid] = v;
    __syncthreads();
    for (int off = 1; off < MAXB; off <<= 1) {
        uint32_t t = (tid >= off) ? buf[tid - off] : 0u;
        __syncthreads();
        buf[tid] += t;
        __syncthreads();
    }
    uint32_t excl = buf[tid] - v;
    if (tid < B) { bases[tid] = excl; gcur[tid] = excl; }
    if (tid == B - 1) bases[B] = buf[tid];
}

// --------------------------------------------------- scatter with local sort
__global__ __launch_bounds__(256) void scatter_kernel(
    const float* __restrict__ lengths,
    const int* __restrict__ src, const int* __restrict__ dst,
    const float2* __restrict__ ztab,
    const float* __restrict__ rmax_ptr,
    uint32_t* __restrict__ gcur,
    uint32_t* __restrict__ records,
    int n_edges, int B, int vec_ok) {
    __shared__ uint32_t srt[2 * CHUNK];      // 32 KB sorted records
    __shared__ uint32_t lh[MAXB];            // counts -> placement cursors
    __shared__ uint32_t lscan[MAXB + 1];     // local segment bounds
    __shared__ uint32_t cur0[MAXB];          // global segment starts
    __shared__ uint32_t tsum[256];
    int tid = threadIdx.x;
    int start = blockIdx.x * CHUNK;
    int n_this = min(CHUNK, n_edges - start);
    bool vec = (n_this == CHUNK) && vec_ok;

    for (int i = tid; i < MAXB; i += 256) lh[i] = 0;
    __syncthreads();

    // phase A: local histogram of bucket ids
    if (vec) {
        for (int it = 0; it < CHUNK / 1024; ++it) {
            int e = start + (it * 256 + tid) * 4;
            int4 S = *reinterpret_cast<const int4*>(src + e);
            int4 D = *reinterpret_cast<const int4*>(dst + e);
            atomicAdd(&lh[S.x >> BSH], 1u); atomicAdd(&lh[D.x >> BSH], 1u);
            atomicAdd(&lh[S.y >> BSH], 1u); atomicAdd(&lh[D.y >> BSH], 1u);
            atomicAdd(&lh[S.z >> BSH], 1u); atomicAdd(&lh[D.z >> BSH], 1u);
            atomicAdd(&lh[S.w >> BSH], 1u); atomicAdd(&lh[D.w >> BSH], 1u);
        }
    } else {
        for (int i = tid; i < n_this; i += 256) {
            atomicAdd(&lh[src[start + i] >> BSH], 1u);
            atomicAdd(&lh[dst[start + i] >> BSH], 1u);
        }
    }
    __syncthreads();

    // local exclusive scan over MAXB=512 (2 elems/thread + 256-scan)
    uint32_t a = lh[2 * tid], b2 = lh[2 * tid + 1];
    tsum[tid] = a + b2;
    __syncthreads();
    for (int off = 1; off < 256; off <<= 1) {
        uint32_t t = (tid >= off) ? tsum[tid - off] : 0u;
        __syncthreads();
        tsum[tid] += t;
        __syncthreads();
    }
    uint32_t excl = tsum[tid] - (a + b2);
    lscan[2 * tid] = excl;
    lscan[2 * tid + 1] = excl + a;
    if (tid == 255) lscan[MAXB] = tsum[255];
    __syncthreads();

    // reserve global space per bucket; reset lh to placement cursors
    for (int i = tid; i < B; i += 256) {
        uint32_t cnt = lscan[i + 1] - lscan[i];
        cur0[i] = cnt ? atomicAdd(&gcur[i], cnt) : 0u;
        lh[i] = lscan[i];
    }
    __syncthreads();

    // phase B: compute energies, place records sorted-by-bucket in LDS
    const float inv_rmax = 1.0f / rmax_ptr[0];
    if (vec) {
        for (int it = 0; it < CHUNK / 1024; ++it) {
            int e = start + (it * 256 + tid) * 4;
            float4 L = *reinterpret_cast<const float4*>(lengths + e);
            int4 S = *reinterpret_cast<const int4*>(src + e);
            int4 D = *reinterpret_cast<const int4*>(dst + e);
            float l[4] = {L.x, L.y, L.z, L.w};
            int s[4] = {S.x, S.y, S.z, S.w};
            int d[4] = {D.x, D.y, D.z, D.w};
            float2 zs[4], zd[4];
#pragma unroll
            for (int k = 0; k < 4; ++k) { zs[k] = ztab[s[k]]; zd[k] = ztab[d[k]]; }
#pragma unroll
            for (int k = 0; k < 4; ++k) {
                float q = edge_energy(l[k], zs[k], zd[k], inv_rmax);
                uint32_t qb = __float_as_uint(q) >> 10;
                uint32_t ps = atomicAdd(&lh[s[k] >> BSH], 1u);
                srt[ps] = ((uint32_t)(s[k] & BMASK) << 22) | qb;
                uint32_t pd = atomicAdd(&lh[d[k] >> BSH], 1u);
                srt[pd] = ((uint32_t)(d[k] & BMASK) << 22) | qb;
            }
        }
    } else {
        for (int i = tid; i < n_this; i += 256) {
            int e = start + i;
            int si = src[e], di = dst[e];
            float q = edge_energy(lengths[e], ztab[si], ztab[di], inv_rmax);
            uint32_t qb = __float_as_uint(q) >> 10;
            uint32_t ps = atomicAdd(&lh[si >> BSH], 1u);
            srt[ps] = ((uint32_t)(si & BMASK) << 22) | qb;
            uint32_t pd = atomicAdd(&lh[di >> BSH], 1u);
            srt[pd] = ((uint32_t)(di & BMASK) << 22) | qb;
        }
    }
    __syncthreads();

    // phase C: emit — consecutive lanes write consecutive positions of one
    // bucket segment -> coalesced near-full-line writes.
    int wv = tid >> 6, ln = tid & 63;
    for (int b = wv; b < B; b += 4) {
        uint32_t s0 = lscan[b], e0 = lscan[b + 1], g = cur0[b];
        for (uint32_t i = s0 + ln; i < e0; i += 64)
            records[g + (i - s0)] = srt[i];
    }
}

// ------------------------------------------------------------------- reduce
__global__ __launch_bounds__(256) void reduce_bucket_kernel(
    const uint32_t* __restrict__ records,
    const uint32_t* __restrict__ bases,
    float* __restrict__ partial, int S, int npad) {
    int b = blockIdx.x, s = blockIdx.y, tid = threadIdx.x;
    __shared__ float acc[(1 << BSH) * 2];
    for (int i = tid; i < (1 << BSH) * 2; i += 256) acc[i] = 0.0f;
    __syncthreads();
    uint32_t s0 = bases[b], e0 = bases[b + 1];
    uint32_t len = e0 - s0;
    uint32_t beg = s0 + (uint32_t)((unsigned long long)len * s / S);
    uint32_t end = s0 + (uint32_t)((unsigned long long)len * (s + 1) / S);
    int rep = tid & 1;
    for (uint32_t p = beg + tid; p < end; p += 256) {
        uint32_t rec = records[p];
        float q = __uint_as_float((rec & 0x3FFFFFu) << 10);
        int local = (int)(rec >> 22);
        atomicAdd(&acc[local * 2 + rep], q);
    }
    __syncthreads();
    for (int i = tid; i < (1 << BSH); i += 256)
        partial[(size_t)s * npad + (b << BSH) + i] = acc[i * 2] + acc[i * 2 + 1];
}

__global__ void combine_kernel(const float* __restrict__ partial,
                               float* __restrict__ out,
                               int n_nodes, int S, int npad) {
    int i = blockIdx.x * blockDim.x + threadIdx.x;
    if (i >= n_nodes) return;
    float t = 0.0f;
    for (int s = 0; s < S; ++s) t += partial[(size_t)s * npad + i];
    out[i] = t;
}

// ----------------------------------------------------------- fallback (R2)
__global__ void zero_out_kernel(float* __restrict__ out, int n) {
    int i = blockIdx.x * blockDim.x + threadIdx.x;
    if (i < n) out[i] = 0.0f;
}

__global__ __launch_bounds__(256) void edge_kernel_atomic(
    const float* __restrict__ lengths,
    const int* __restrict__ src_idx,
    const int* __restrict__ dst_idx,
    const float2* __restrict__ ztab,
    const float* __restrict__ rmax_ptr,
    float* __restrict__ out,
    int n_edges) {
    const float inv_rmax = 1.0f / rmax_ptr[0];
    int t = blockIdx.x * blockDim.x + threadIdx.x;
    int base = t * 4;
    if (base + 3 < n_edges) {
        float4 L = *reinterpret_cast<const float4*>(lengths + base);
        int4 S = *reinterpret_cast<const int4*>(src_idx + base);
        int4 D = *reinterpret_cast<const int4*>(dst_idx + base);
        float l[4] = {L.x, L.y, L.z, L.w};
        int s[4] = {S.x, S.y, S.z, S.w};
        int d[4] = {D.x, D.y, D.z, D.w};
        float2 zs[4], zd[4];
#pragma unroll
        for (int k = 0; k < 4; ++k) { zs[k] = ztab[s[k]]; zd[k] = ztab[d[k]]; }
#pragma unroll
        for (int k = 0; k < 4; ++k) {
            float q = edge_energy(l[k], zs[k], zd[k], inv_rmax);
            unsafeAtomicAdd(&out[s[k]], q);
            unsafeAtomicAdd(&out[d[k]], q);
        }
    } else if (base < n_edges) {
        for (int e = base; e < n_edges; ++e) {
            int si = src_idx[e], di = dst_idx[e];
            float q = edge_energy(lengths[e], ztab[si], ztab[di], inv_rmax);
            unsafeAtomicAdd(&out[si], q);
            unsafeAtomicAdd(&out[di], q);
        }
    }
}

// ---------------------------------------------------------------- launcher
extern "C" void kernel_launch(void* const* d_in, const int* in_sizes, int n_in,
                              void* d_out, int out_size, void* d_ws, size_t ws_size,
                              hipStream_t stream) {
    const float* lengths        = (const float*)d_in[0];
    const float* node_attrs     = (const float*)d_in[1];
    const int*   edge_index     = (const int*)d_in[2];
    const float* atomic_numbers = (const float*)d_in[3];
    const float* rmax_ptr       = (const float*)d_in[4];

    int n_edges = in_sizes[0];
    int n_elem  = in_sizes[3];
    int n_nodes = out_size;
    float* out = (float*)d_out;

    const int* src = edge_index;
    const int* dst = edge_index + n_edges;

    int B    = ((n_nodes - 1) >> BSH) + 1;
    int NB   = (n_edges + CHUNK - 1) / CHUNK;
    int npad = B << BSH;
    int vec_ok = ((n_edges & 3) == 0) ? 1 : 0;   // int4 alignment of dst

    // ws layout: records | totals(B) | bases(B+1) | gcur(B) | partial(S*npad)
    //            | ztab(n_nodes float2)
    size_t rec_bytes = (size_t)2 * n_edges * sizeof(uint32_t);
    size_t tot_off   = rec_bytes;
    size_t base_off  = tot_off + (size_t)B * 4;
    size_t gcur_off  = base_off + (size_t)(B + 1) * 4;
    size_t part_off  = (gcur_off + (size_t)B * 4 + 255) & ~(size_t)255;

    int S = MAXS;
    size_t need = 0;
    for (; S >= 1; --S) {
        size_t zoff = (part_off + (size_t)S * npad * 4 + 7) & ~(size_t)7;
        need = zoff + (size_t)n_nodes * sizeof(float2);
        if (need <= ws_size) break;
    }

    int nb_nodes = (n_nodes + 255) / 256;

    if (B <= MAXB && S >= 1) {
        size_t zoff = (part_off + (size_t)S * npad * 4 + 7) & ~(size_t)7;
        uint32_t* records = (uint32_t*)d_ws;
        uint32_t* totals  = (uint32_t*)((char*)d_ws + tot_off);
        uint32_t* bases   = (uint32_t*)((char*)d_ws + base_off);
        uint32_t* gcur    = (uint32_t*)((char*)d_ws + gcur_off);
        float*    partial = (float*)((char*)d_ws + part_off);
        float2*   ztab    = (float2*)((char*)d_ws + zoff);

        hipMemsetAsync((char*)d_ws + tot_off, 0, (size_t)(3 * B + 1) * 4, stream);
        prep_nodes_kernel<<<nb_nodes, 256, 0, stream>>>(
            node_attrs, atomic_numbers, ztab, n_nodes, n_elem);
        hist_tot_kernel<<<NB, 256, 0, stream>>>(src, dst, totals, n_edges, B, vec_ok);
        scan_total_kernel<<<1, MAXB, 0, stream>>>(totals, bases, gcur, B);
        scatter_kernel<<<NB, 256, 0, stream>>>(
            lengths, src, dst, ztab, rmax_ptr, gcur, records, n_edges, B, vec_ok);
        reduce_bucket_kernel<<<dim3(B, S), 256, 0, stream>>>(
            records, bases, partial, S, npad);
        combine_kernel<<<nb_nodes, 256, 0, stream>>>(partial, out, n_nodes, S, npad);
    } else {
        // fallback: replicated-atomic path (R2)
        int stride = ((n_nodes + 49) / 2) * 2;
        int R = 16;
        while (R > 1 &&
               (size_t)R * stride * sizeof(float) + (size_t)n_nodes * sizeof(float2)
                   > ws_size)
            R >>= 1;
        float2* ztab = (float2*)((char*)d_ws + (size_t)R * stride * sizeof(float));
        hipMemsetAsync(d_ws, 0, (size_t)R * stride * sizeof(float), stream);
        prep_nodes_kernel<<<nb_nodes, 256, 0, stream>>>(
            node_attrs, atomic_numbers, ztab, n_nodes, n_elem);
        zero_out_kernel<<<nb_nodes, 256, 0, stream>>>(out, n_nodes);
        int n_thread4 = (n_edges + 3) / 4;
        int nb_edges = (n_thread4 + 255) / 256;
        edge_kernel_atomic<<<nb_edges, 256, 0, stream>>>(
            lengths, src, dst, ztab, rmax_ptr, out, n_edges);
    }
}

// Round 5
// 273.115 us; speedup vs baseline: 2.7291x; 1.1993x over previous
//
#include <hip/hip_runtime.h>
#include <hip/hip_bf16.h>
#include <stdint.h>

// ---------------------------------------------------------------------------
// PairRepulsionSwitch: per-edge ZBL + r^-12 repulsion, quarter-summed to both
// endpoint nodes.
//
// R1/R2: global fp32 atomics memory-side rate-limited (~20G/s) -> 655/621us.
// R3: bucket binning -> 373us (write amplification + low occupancy).
// R4: LDS counting sort -> 327us; tax = ~51M LDS atomics across 4 dispatches
//     + edges read twice + 3M bank conflicts in scatter.
// R5: no sort. Node-range multipass: P=ceil(n/12800) ranges x S=96 edge
//     slices. Block (p,s) filters slice s for endpoints in range p and does
//     ds_add_f32 into a 50KB LDS accumulator (12.8M LDS atomics total, the
//     raw minimum; zero global atomics, zero records). Swizzle i=p*S+s with
//     S%8==0 puts all 8 p-variants of a slice on one XCD -> edge re-reads
//     served by L2. 768 blocks = 3/CU, all co-resident. Epilogue: dump
//     partials (38MB), combine sums S rows per node.
// ---------------------------------------------------------------------------

#define KE_CONST 14.3996454784255f
constexpr float INV_AC = 1.0f / (0.88534f * 0.52917721092f);

#define NR 12800             // nodes per range: 50 KB LDS -> 3 blocks/CU
#define SMAX 96              // edge slices (multiple of 8)

// ---------------------------------------------------------------- shared math
__device__ __forceinline__ float edge_energy(float len, float2 zi, float2 zj,
                                             float inv_rmax) {
    float r = fmaxf(len, 0.2f);                 // R_MIN clamp
    float inv_r = 1.0f / r;

    // poly cutoff: (1 - clip(r/r_max,0,1))^6
    float u = fmaxf(1.0f - r * inv_rmax, 0.0f);
    float u2 = u * u;
    float pc = u2 * u2 * u2;

    // ZBL screened Coulomb
    float x = r * (zi.y + zj.y) * INV_AC;
    float phi = 0.1818f   * __expf(-3.2f    * x)
              + 0.5099f   * __expf(-0.9423f * x)
              + 0.2802f   * __expf(-0.4029f * x)
              + 0.02817f  * __expf(-0.2016f * x);
    float v_zbl = KE_CONST * zi.x * zj.x * phi * inv_r * pc;

    // C12 / r^12 with smoothstep switch at rc=1.5, width=0.2
    float ir2 = inv_r * inv_r;
    float ir4 = ir2 * ir2;
    float ir12 = ir4 * ir4 * ir4;
    float t = fminf(fmaxf((1.5f - r) * 5.0f, 0.0f), 1.0f);  // /width=0.2
    float sm = t * t * (3.0f - 2.0f * t);
    float v_r12 = 1e-4f * ir12 * pc * sm;

    return 0.25f * (v_zbl + v_r12);             // quarter to each endpoint
}

__global__ void prep_nodes_kernel(const float* __restrict__ node_attrs,
                                  const float* __restrict__ atomic_numbers,
                                  float2* __restrict__ ztab,
                                  int n_nodes, int n_elem) {
    int i = blockIdx.x * blockDim.x + threadIdx.x;
    if (i >= n_nodes) return;
    float z = 0.0f;
    for (int k = 0; k < n_elem; ++k)
        z += node_attrs[i * n_elem + k] * atomic_numbers[k];
    ztab[i] = make_float2(z, powf(z, 0.23f));
}

// --------------------------------------------------------------- accumulate
__global__ __launch_bounds__(256) void accum_kernel(
    const float* __restrict__ lengths,
    const int* __restrict__ src, const int* __restrict__ dst,
    const float2* __restrict__ ztab,
    const float* __restrict__ rmax_ptr,
    float* __restrict__ partial,     // S rows of npad floats
    int n_edges, int S, int EPB, int npad, int vec_ok) {
    __shared__ float acc[NR];
    int s = blockIdx.x % S;          // S%8==0: same-s blocks share an XCD
    int p = blockIdx.x / S;
    int tid = threadIdx.x;
    for (int i = tid; i < NR; i += 256) acc[i] = 0.0f;
    __syncthreads();

    const float inv_rmax = 1.0f / rmax_ptr[0];
    const unsigned base = (unsigned)p * NR;
    int e0 = s * EPB;
    int e1 = min(e0 + EPB, n_edges);

    if (vec_ok) {
        int nquad = (e1 - e0) >> 2;
        for (int q4 = tid; q4 < nquad; q4 += 256) {
            int e = e0 + q4 * 4;
            int4 Sv = *reinterpret_cast<const int4*>(src + e);
            int4 Dv = *reinterpret_cast<const int4*>(dst + e);
            int sv[4] = {Sv.x, Sv.y, Sv.z, Sv.w};
            int dv[4] = {Dv.x, Dv.y, Dv.z, Dv.w};
#pragma unroll
            for (int k = 0; k < 4; ++k) {
                unsigned ls = (unsigned)sv[k] - base;
                unsigned ld = (unsigned)dv[k] - base;
                bool hs = ls < NR, hd = ld < NR;
                if (hs || hd) {
                    float q = edge_energy(lengths[e + k], ztab[sv[k]],
                                          ztab[dv[k]], inv_rmax);
                    if (hs) atomicAdd(&acc[ls], q);
                    if (hd) atomicAdd(&acc[ld], q);
                }
            }
        }
        for (int e = e0 + (nquad << 2) + tid; e < e1; e += 256) {
            int si = src[e], di = dst[e];
            unsigned ls = (unsigned)si - base;
            unsigned ld = (unsigned)di - base;
            bool hs = ls < NR, hd = ld < NR;
            if (hs || hd) {
                float q = edge_energy(lengths[e], ztab[si], ztab[di], inv_rmax);
                if (hs) atomicAdd(&acc[ls], q);
                if (hd) atomicAdd(&acc[ld], q);
            }
        }
    } else {
        for (int e = e0 + tid; e < e1; e += 256) {
            int si = src[e], di = dst[e];
            unsigned ls = (unsigned)si - base;
            unsigned ld = (unsigned)di - base;
            bool hs = ls < NR, hd = ld < NR;
            if (hs || hd) {
                float q = edge_energy(lengths[e], ztab[si], ztab[di], inv_rmax);
                if (hs) atomicAdd(&acc[ls], q);
                if (hd) atomicAdd(&acc[ld], q);
            }
        }
    }
    __syncthreads();

    float* __restrict__ row = partial + (size_t)s * npad + base;
    for (int i = tid; i < NR; i += 256) row[i] = acc[i];
}

__global__ void combine_kernel(const float* __restrict__ partial,
                               float* __restrict__ out,
                               int n_nodes, int S, int npad) {
    int i = blockIdx.x * blockDim.x + threadIdx.x;
    if (i >= n_nodes) return;
    float t = 0.0f;
    for (int s = 0; s < S; ++s)
        t += partial[(size_t)s * npad + i];
    out[i] = t;
}

// ----------------------------------------------------------- fallback (R2)
__global__ void zero_out_kernel(float* __restrict__ out, int n) {
    int i = blockIdx.x * blockDim.x + threadIdx.x;
    if (i < n) out[i] = 0.0f;
}

__global__ __launch_bounds__(256) void edge_kernel_atomic(
    const float* __restrict__ lengths,
    const int* __restrict__ src_idx,
    const int* __restrict__ dst_idx,
    const float2* __restrict__ ztab,
    const float* __restrict__ rmax_ptr,
    float* __restrict__ out,
    int n_edges) {
    const float inv_rmax = 1.0f / rmax_ptr[0];
    int t = blockIdx.x * blockDim.x + threadIdx.x;
    int base = t * 4;
    if (base + 3 < n_edges) {
        float4 L = *reinterpret_cast<const float4*>(lengths + base);
        int4 S = *reinterpret_cast<const int4*>(src_idx + base);
        int4 D = *reinterpret_cast<const int4*>(dst_idx + base);
        float l[4] = {L.x, L.y, L.z, L.w};
        int s[4] = {S.x, S.y, S.z, S.w};
        int d[4] = {D.x, D.y, D.z, D.w};
        float2 zs[4], zd[4];
#pragma unroll
        for (int k = 0; k < 4; ++k) { zs[k] = ztab[s[k]]; zd[k] = ztab[d[k]]; }
#pragma unroll
        for (int k = 0; k < 4; ++k) {
            float q = edge_energy(l[k], zs[k], zd[k], inv_rmax);
            unsafeAtomicAdd(&out[s[k]], q);
            unsafeAtomicAdd(&out[d[k]], q);
        }
    } else if (base < n_edges) {
        for (int e = base; e < n_edges; ++e) {
            int si = src_idx[e], di = dst_idx[e];
            float q = edge_energy(lengths[e], ztab[si], ztab[di], inv_rmax);
            unsafeAtomicAdd(&out[si], q);
            unsafeAtomicAdd(&out[di], q);
        }
    }
}

// ---------------------------------------------------------------- launcher
extern "C" void kernel_launch(void* const* d_in, const int* in_sizes, int n_in,
                              void* d_out, int out_size, void* d_ws, size_t ws_size,
                              hipStream_t stream) {
    const float* lengths        = (const float*)d_in[0];
    const float* node_attrs     = (const float*)d_in[1];
    const int*   edge_index     = (const int*)d_in[2];
    const float* atomic_numbers = (const float*)d_in[3];
    const float* rmax_ptr       = (const float*)d_in[4];

    int n_edges = in_sizes[0];
    int n_elem  = in_sizes[3];
    int n_nodes = out_size;
    float* out = (float*)d_out;

    const int* src = edge_index;
    const int* dst = edge_index + n_edges;

    int P    = (n_nodes + NR - 1) / NR;
    int npad = P * NR;
    int vec_ok = ((n_edges & 3) == 0) ? 1 : 0;   // int4 alignment of dst

    // Pick S (multiple of 8) so partial + ztab fit the workspace.
    int S = SMAX;
    size_t zoff = 0, need = 0;
    for (; S >= 8; S -= 8) {
        zoff = ((size_t)S * npad * sizeof(float) + 7) & ~(size_t)7;
        need = zoff + (size_t)n_nodes * sizeof(float2);
        if (need <= ws_size) break;
    }

    int nb_nodes = (n_nodes + 255) / 256;

    if (S >= 8) {
        float*  partial = (float*)d_ws;
        float2* ztab    = (float2*)((char*)d_ws + zoff);
        int EPB = (((n_edges + S - 1) / S) + 3) & ~3;   // slice size, mult of 4

        prep_nodes_kernel<<<nb_nodes, 256, 0, stream>>>(
            node_attrs, atomic_numbers, ztab, n_nodes, n_elem);
        accum_kernel<<<P * S, 256, 0, stream>>>(
            lengths, src, dst, ztab, rmax_ptr, partial,
            n_edges, S, EPB, npad, vec_ok);
        combine_kernel<<<nb_nodes, 256, 0, stream>>>(
            partial, out, n_nodes, S, npad);
    } else {
        // fallback: replicated-atomic path (R2)
        int stride = ((n_nodes + 49) / 2) * 2;
        int R = 16;
        while (R > 1 &&
               (size_t)R * stride * sizeof(float) + (size_t)n_nodes * sizeof(float2)
                   > ws_size)
            R >>= 1;
        float2* ztab = (float2*)((char*)d_ws + (size_t)R * stride * sizeof(float));
        hipMemsetAsync(d_ws, 0, (size_t)R * stride * sizeof(float), stream);
        prep_nodes_kernel<<<nb_nodes, 256, 0, stream>>>(
            node_attrs, atomic_numbers, ztab, n_nodes, n_elem);
        zero_out_kernel<<<nb_nodes, 256, 0, stream>>>(out, n_nodes);
        int n_thread4 = (n_edges + 3) / 4;
        int nb_edges = (n_thread4 + 255) / 256;
        edge_kernel_atomic<<<nb_edges, 256, 0, stream>>>(
            lengths, src, dst, ztab, rmax_ptr, out, n_edges);
    }
}